// Round 4
// baseline (352.495 us; speedup 1.0000x reference)
//
#include <hip/hip_runtime.h>

#define HIDDEN 128
#define NBUCKETS 20
#define ROWS 32

typedef unsigned int uint32;
typedef unsigned short u16;

__device__ __forceinline__ u16 f32_to_bf16(float f) {
    uint32 u = __float_as_uint(f);
    return (u16)((u + 0x7fffu + ((u >> 16) & 1u)) >> 16);
}

// Register-blocked skinny GEMM, no LDS: each block computes y[base..base+31][:]
// and z[base..base+31][:] in bf16 (one output column per thread). x is read at
// wave-uniform addresses (scalarizable to s_load); W1 columns are streamed as
// coalesced vector loads (full W1 per block = L2-resident). Also emits x16.
__global__ void precompute_kernel(const float* __restrict__ x,
                                  const float* __restrict__ W1,
                                  u16* __restrict__ y16,
                                  u16* __restrict__ z16,
                                  u16* __restrict__ x16,
                                  int n_nodes) {
    int base = blockIdx.x * ROWS;
    int t = threadIdx.x;  // 0..255
    int rows = min(ROWS, n_nodes - base);

    // bf16 copy of x for this block's rows (independent of GEMM, no sync needed).
    {
        const float4* xf4 = (const float4*)(x + (size_t)base * HIDDEN);
        int total4 = rows * (HIDDEN / 4);
        for (int i = t; i < total4; i += 256) {
            float4 v = xf4[i];
            ushort4 o;
            o.x = f32_to_bf16(v.x); o.y = f32_to_bf16(v.y);
            o.z = f32_to_bf16(v.z); o.w = f32_to_bf16(v.w);
            *(ushort4*)(x16 + (size_t)base * HIDDEN + i * 4) = o;
        }
    }

    int j = t & (HIDDEN - 1);
    int half = t >> 7;  // 0 -> y, 1 -> z
    const float* __restrict__ Wb = W1 + half * HIDDEN * HIDDEN;
    const float* __restrict__ xrow = x + (size_t)base * HIDDEN;

    float acc[ROWS];
#pragma unroll
    for (int r = 0; r < ROWS; ++r) acc[r] = 0.f;

    for (int k0 = 0; k0 < HIDDEN; k0 += 16) {
        float w[16];
#pragma unroll
        for (int i = 0; i < 16; ++i) w[i] = Wb[(k0 + i) * HIDDEN + j];
#pragma unroll
        for (int r = 0; r < ROWS; ++r) {
            int rr = (base + r < n_nodes) ? r : 0;  // uniform clamp, no OOB
            const float4* xr = (const float4*)(xrow + rr * HIDDEN + k0);
            float4 a = xr[0], b = xr[1], c = xr[2], d = xr[3];
            acc[r] = fmaf(a.x, w[0],  acc[r]);
            acc[r] = fmaf(a.y, w[1],  acc[r]);
            acc[r] = fmaf(a.z, w[2],  acc[r]);
            acc[r] = fmaf(a.w, w[3],  acc[r]);
            acc[r] = fmaf(b.x, w[4],  acc[r]);
            acc[r] = fmaf(b.y, w[5],  acc[r]);
            acc[r] = fmaf(b.z, w[6],  acc[r]);
            acc[r] = fmaf(b.w, w[7],  acc[r]);
            acc[r] = fmaf(c.x, w[8],  acc[r]);
            acc[r] = fmaf(c.y, w[9],  acc[r]);
            acc[r] = fmaf(c.z, w[10], acc[r]);
            acc[r] = fmaf(c.w, w[11], acc[r]);
            acc[r] = fmaf(d.x, w[12], acc[r]);
            acc[r] = fmaf(d.y, w[13], acc[r]);
            acc[r] = fmaf(d.z, w[14], acc[r]);
            acc[r] = fmaf(d.w, w[15], acc[r]);
        }
    }

    u16* __restrict__ dst = half ? z16 : y16;
#pragma unroll
    for (int r = 0; r < ROWS; ++r)
        if (base + r < n_nodes)
            dst[(size_t)(base + r) * HIDDEN + j] = f32_to_bf16(acc[r]);
}

// Histogram of target degrees; block 0 also computes de_dot[b] = table[b]·W2[128:].
__global__ void count_kernel(const int* __restrict__ tgt,
                             int* __restrict__ cnt, int n_edges,
                             const float* __restrict__ table,
                             const float* __restrict__ W2,
                             float* __restrict__ de_dot) {
    int e = blockIdx.x * blockDim.x + threadIdx.x;
    if (e < n_edges) atomicAdd(&cnt[tgt[e]], 1);
    if (blockIdx.x == 0 && threadIdx.x < NBUCKETS) {
        float a = 0.f;
        for (int k = 0; k < HIDDEN; ++k)
            a = fmaf(table[threadIdx.x * HIDDEN + k], W2[HIDDEN + k], a);
        de_dot[threadIdx.x] = a;
    }
}

// Per-block exclusive prescan of cnt + per-block totals.
__global__ void scan_blocks_kernel(const int* __restrict__ cnt,
                                   int* __restrict__ prescan,
                                   int* __restrict__ partial,
                                   int n_nodes) {
    __shared__ int sh[256];
    int t = threadIdx.x;
    int i = blockIdx.x * 256 + t;
    int v = (i < n_nodes) ? cnt[i] : 0;
    sh[t] = v;
    __syncthreads();
    for (int d = 1; d < 256; d <<= 1) {
        int add = (t >= d) ? sh[t - d] : 0;
        __syncthreads();
        sh[t] += add;
        __syncthreads();
    }
    if (i < n_nodes) prescan[i] = sh[t] - v;
    if (t == 255) partial[blockIdx.x] = sh[t];
}

// Exclusive scan of block totals (nb <= 256).
__global__ void scan_partials_kernel(int* __restrict__ partial, int nb) {
    __shared__ int sh[256];
    int t = threadIdx.x;
    int v = (t < nb) ? partial[t] : 0;
    sh[t] = v;
    __syncthreads();
    for (int d = 1; d < 256; d <<= 1) {
        int add = (t >= d) ? sh[t - d] : 0;
        __syncthreads();
        sh[t] += add;
        __syncthreads();
    }
    if (t < nb) partial[t] = sh[t] - v;   // exclusive, in place
}

// Scatter edges into CSR order, pre-gathering src id and de_dot scalar.
__global__ void scatter_kernel(const int* __restrict__ edge_index,
                               const int* __restrict__ distances,
                               const int* __restrict__ prescan,
                               const int* __restrict__ partial,
                               const float* __restrict__ de_dot,
                               int* __restrict__ cursor,
                               int* __restrict__ csr_src,
                               float* __restrict__ csr_ded,
                               int n_edges) {
    int e = blockIdx.x * blockDim.x + threadIdx.x;
    if (e >= n_edges) return;
    int s = edge_index[e];
    int t = edge_index[n_edges + e];
    int base = prescan[t] + partial[t >> 8];
    int pos = atomicAdd(&cursor[t], 1);
    csr_src[base + pos] = s;
    csr_ded[base + pos] = de_dot[distances[e] / 50];
}

__device__ __forceinline__ float bf_lo(uint32 u) { return __uint_as_float(u << 16); }
__device__ __forceinline__ float bf_hi(uint32 u) { return __uint_as_float(u & 0xffff0000u); }

// One wave per node: fused attention + aggregation + normalize + relu.
// bf16 gathers (uint = 2 features per lane), edge loop unrolled x2 for ILP.
__global__ void aggregate_kernel(const u16* __restrict__ x16,
                                 const u16* __restrict__ y16,
                                 const u16* __restrict__ z16,
                                 const float* __restrict__ W2,
                                 const int* __restrict__ csr_src,
                                 const float* __restrict__ csr_ded,
                                 const int* __restrict__ prescan,
                                 const int* __restrict__ partial,
                                 const int* __restrict__ cnt,
                                 float* __restrict__ out,
                                 int n_nodes) {
    int lane = threadIdx.x & 63;
    int t = blockIdx.x * (blockDim.x >> 6) + (threadIdx.x >> 6);
    if (t >= n_nodes) return;

    int base = prescan[t] + partial[t >> 8];
    int deg = cnt[t];

    const uint32* __restrict__ yp = (const uint32*)y16;
    const uint32* __restrict__ xp = (const uint32*)x16;

    uint32 zv = ((const uint32*)z16)[(size_t)t * 64 + lane];
    float z0 = bf_lo(zv), z1 = bf_hi(zv);
    int f0 = lane * 2;
    float2 wv = *(const float2*)(W2 + f0);

    float acc0 = 0.f, acc1 = 0.f, attsum = 0.f;

    for (int b = 0; b < deg; b += 64) {
        int nb = min(64, deg - b);
        int sv = 0;
        float dedv = 0.f;
        if (lane < nb) {
            sv = csr_src[base + b + lane];
            dedv = csr_ded[base + b + lane];
        }
        int j = 0;
        for (; j + 2 <= nb; j += 2) {
            int sA = __shfl(sv, j, 64);
            int sB = __shfl(sv, j + 1, 64);
            float dA = __shfl(dedv, j, 64);
            float dB = __shfl(dedv, j + 1, 64);
            uint32 ya = yp[(size_t)sA * 64 + lane];
            uint32 yb = yp[(size_t)sB * 64 + lane];
            float hA0 = bf_lo(ya) + z0, hA1 = bf_hi(ya) + z1;
            float hB0 = bf_lo(yb) + z0, hB1 = bf_hi(yb) + z1;
            hA0 = fmaxf(hA0, 0.2f * hA0); hA1 = fmaxf(hA1, 0.2f * hA1);
            hB0 = fmaxf(hB0, 0.2f * hB0); hB1 = fmaxf(hB1, 0.2f * hB1);
            float pA = fmaf(hA0, wv.x, hA1 * wv.y);
            float pB = fmaf(hB0, wv.x, hB1 * wv.y);
#pragma unroll
            for (int off = 32; off > 0; off >>= 1) {
                pA += __shfl_xor(pA, off, 64);
                pB += __shfl_xor(pB, off, 64);
            }
            float sigA = 1.f / (1.f + __expf(-(pA + dA)));
            float sigB = 1.f / (1.f + __expf(-(pB + dB)));
            float attA = __expf(sigA);
            float attB = __expf(sigB);
            uint32 xa = xp[(size_t)sA * 64 + lane];
            uint32 xb = xp[(size_t)sB * 64 + lane];
            acc0 = fmaf(attA, bf_lo(xa), acc0);
            acc1 = fmaf(attA, bf_hi(xa), acc1);
            acc0 = fmaf(attB, bf_lo(xb), acc0);
            acc1 = fmaf(attB, bf_hi(xb), acc1);
            attsum += attA + attB;
        }
        for (; j < nb; ++j) {
            int sA = __shfl(sv, j, 64);
            float dA = __shfl(dedv, j, 64);
            uint32 ya = yp[(size_t)sA * 64 + lane];
            float hA0 = bf_lo(ya) + z0, hA1 = bf_hi(ya) + z1;
            hA0 = fmaxf(hA0, 0.2f * hA0); hA1 = fmaxf(hA1, 0.2f * hA1);
            float pA = fmaf(hA0, wv.x, hA1 * wv.y);
#pragma unroll
            for (int off = 32; off > 0; off >>= 1) pA += __shfl_xor(pA, off, 64);
            float attA = __expf(1.f / (1.f + __expf(-(pA + dA))));
            uint32 xa = xp[(size_t)sA * 64 + lane];
            acc0 = fmaf(attA, bf_lo(xa), acc0);
            acc1 = fmaf(attA, bf_hi(xa), acc1);
            attsum += attA;
        }
    }
    float inv = 1.f / (attsum + 1e-6f);
    float2 o;
    o.x = fmaxf(acc0 * inv, 0.f);
    o.y = fmaxf(acc1 * inv, 0.f);
    *(float2*)(out + (size_t)t * HIDDEN + f0) = o;
}

static inline size_t align16(size_t v) { return (v + 15) & ~(size_t)15; }

extern "C" void kernel_launch(void* const* d_in, const int* in_sizes, int n_in,
                              void* d_out, int out_size, void* d_ws, size_t ws_size,
                              hipStream_t stream) {
    const float* x          = (const float*)d_in[0];
    const int*   edge_index = (const int*)d_in[1];
    const int*   distances  = (const int*)d_in[2];
    const float* W1         = (const float*)d_in[3];
    const float* W2         = (const float*)d_in[4];
    const float* table      = (const float*)d_in[5];

    int n_nodes = in_sizes[0] / HIDDEN;
    int n_edges = in_sizes[1] / 2;
    float* out = (float*)d_out;

    // Workspace layout (16B-aligned sections)
    char* p = (char*)d_ws;
    int* cnt      = (int*)p;                 p += align16((size_t)n_nodes * 4);
    int* cursor   = (int*)p;                 p += align16((size_t)n_nodes * 4);
    int* prescan  = (int*)p;                 p += align16((size_t)n_nodes * 4);
    int* partial  = (int*)p;                 p += align16(256 * 4);
    int* csr_src  = (int*)p;                 p += align16((size_t)n_edges * 4);
    float* csr_ded = (float*)p;              p += align16((size_t)n_edges * 4);
    float* de_dot  = (float*)p;              p += align16(32 * 4);
    u16* y16       = (u16*)p;                p += align16((size_t)n_nodes * HIDDEN * 2);
    u16* z16       = (u16*)p;                p += align16((size_t)n_nodes * HIDDEN * 2);
    u16* x16       = (u16*)p;

    hipMemsetAsync(cnt, 0, (size_t)2 * ((size_t)align16((size_t)n_nodes * 4)), stream);

    int pblocks = (n_nodes + ROWS - 1) / ROWS;
    precompute_kernel<<<pblocks, 256, 0, stream>>>(x, W1, y16, z16, x16, n_nodes);

    const int* tgt = edge_index + n_edges;
    count_kernel<<<(n_edges + 255) / 256, 256, 0, stream>>>(tgt, cnt, n_edges,
                                                            table, W2, de_dot);

    int nb = (n_nodes + 255) / 256;
    scan_blocks_kernel<<<nb, 256, 0, stream>>>(cnt, prescan, partial, n_nodes);
    scan_partials_kernel<<<1, 256, 0, stream>>>(partial, nb);

    scatter_kernel<<<(n_edges + 255) / 256, 256, 0, stream>>>(
        edge_index, distances, prescan, partial, de_dot, cursor,
        csr_src, csr_ded, n_edges);

    const int waves_per_block = 4;
    int ablocks = (n_nodes + waves_per_block - 1) / waves_per_block;
    aggregate_kernel<<<ablocks, 64 * waves_per_block, 0, stream>>>(
        x16, y16, z16, W2, csr_src, csr_ded, prescan, partial, cnt, out, n_nodes);
}

// Round 5
// 228.876 us; speedup vs baseline: 1.5401x; 1.5401x over previous
//
#include <hip/hip_runtime.h>

#define HIDDEN 128
#define NBUCKETS 20

typedef unsigned int uint32;
typedef unsigned short u16;
typedef __attribute__((ext_vector_type(8))) short bf16x8;
typedef __attribute__((ext_vector_type(4))) float f32x4;

__device__ __forceinline__ u16 f32_to_bf16(float f) {
    uint32 u = __float_as_uint(f);
    return (u16)((u + 0x7fffu + ((u >> 16) & 1u)) >> 16);
}

// W1T[n][k] (bf16, [256][128]): n<128 -> W1[k][n] (y cols), n>=128 -> W1[128+k][n-128] (z cols).
__global__ void prep_kernel(const float* __restrict__ W1, u16* __restrict__ W1T) {
    int idx = blockIdx.x * 256 + threadIdx.x;  // 0..32767
    int n = idx >> 7, k = idx & 127;
    int srow = (n < 128) ? k : (128 + k);
    int scol = n & 127;
    W1T[idx] = f32_to_bf16(W1[srow * HIDDEN + scol]);
}

// MFMA skinny GEMM: one wave per 16-row tile computes y16/z16 for those rows
// (16x256 output = 16 col-tiles x 4 K-steps of mfma_f32_16x16x32_bf16).
// Also emits x16 (bf16 copy of x) from the already-loaded A values.
__global__ void mfma_gemm_kernel(const float* __restrict__ x,
                                 const u16* __restrict__ W1T,
                                 u16* __restrict__ y16,
                                 u16* __restrict__ z16,
                                 u16* __restrict__ x16,
                                 int n_nodes) {
    int wid = (blockIdx.x * blockDim.x + threadIdx.x) >> 6;  // row-tile index
    int lane = threadIdx.x & 63;
    int row_base = wid * 16;
    if (row_base >= n_nodes) return;

    int m = lane & 15;        // A row / C col
    int kb = lane >> 4;       // k-chunk 0..3 (8 elems each)
    int row = row_base + m;
    int rowc = (row < n_nodes) ? row : (n_nodes - 1);  // clamp (tail safety)

    // A fragments for the 4 K-steps; convert f32 -> bf16; store x16.
    bf16x8 afrag[4];
    const float* xr = x + (size_t)rowc * HIDDEN + kb * 8;
#pragma unroll
    for (int ks = 0; ks < 4; ++ks) {
        float4 v0 = *(const float4*)(xr + ks * 32);
        float4 v1 = *(const float4*)(xr + ks * 32 + 4);
        bf16x8 a;
        a[0] = (short)f32_to_bf16(v0.x); a[1] = (short)f32_to_bf16(v0.y);
        a[2] = (short)f32_to_bf16(v0.z); a[3] = (short)f32_to_bf16(v0.w);
        a[4] = (short)f32_to_bf16(v1.x); a[5] = (short)f32_to_bf16(v1.y);
        a[6] = (short)f32_to_bf16(v1.z); a[7] = (short)f32_to_bf16(v1.w);
        afrag[ks] = a;
        if (row < n_nodes)
            *(bf16x8*)(x16 + (size_t)row * HIDDEN + ks * 32 + kb * 8) = a;
    }

#pragma unroll
    for (int ct = 0; ct < 16; ++ct) {
        int col = ct * 16 + m;  // output col 0..255 (C col = lane&15)
        const u16* bp = W1T + (size_t)col * HIDDEN + kb * 8;
        f32x4 acc = {0.f, 0.f, 0.f, 0.f};
#pragma unroll
        for (int ks = 0; ks < 4; ++ks) {
            bf16x8 b = *(const bf16x8*)(bp + ks * 32);
            acc = __builtin_amdgcn_mfma_f32_16x16x32_bf16(afrag[ks], b, acc, 0, 0, 0);
        }
        // C/D: col = lane&15, row = (lane>>4)*4 + e   [HW-verified m89/m91]
        u16* dst = (col < HIDDEN) ? (y16 + col) : (z16 + col - HIDDEN);
        int r0 = row_base + kb * 4;
#pragma unroll
        for (int e = 0; e < 4; ++e)
            if (r0 + e < n_nodes)
                dst[(size_t)(r0 + e) * HIDDEN] = f32_to_bf16(acc[e]);
    }
}

// Histogram of target degrees; block 0 also computes de_dot[b] = table[b]·W2[128:].
__global__ void count_kernel(const int* __restrict__ tgt,
                             int* __restrict__ cnt, int n_edges,
                             const float* __restrict__ table,
                             const float* __restrict__ W2,
                             float* __restrict__ de_dot) {
    int e = blockIdx.x * blockDim.x + threadIdx.x;
    if (e < n_edges) atomicAdd(&cnt[tgt[e]], 1);
    if (blockIdx.x == 0 && threadIdx.x < NBUCKETS) {
        float a = 0.f;
        for (int k = 0; k < HIDDEN; ++k)
            a = fmaf(table[threadIdx.x * HIDDEN + k], W2[HIDDEN + k], a);
        de_dot[threadIdx.x] = a;
    }
}

// Per-block exclusive prescan of cnt + per-block totals.
__global__ void scan_blocks_kernel(const int* __restrict__ cnt,
                                   int* __restrict__ prescan,
                                   int* __restrict__ partial,
                                   int n_nodes) {
    __shared__ int sh[256];
    int t = threadIdx.x;
    int i = blockIdx.x * 256 + t;
    int v = (i < n_nodes) ? cnt[i] : 0;
    sh[t] = v;
    __syncthreads();
    for (int d = 1; d < 256; d <<= 1) {
        int add = (t >= d) ? sh[t - d] : 0;
        __syncthreads();
        sh[t] += add;
        __syncthreads();
    }
    if (i < n_nodes) prescan[i] = sh[t] - v;
    if (t == 255) partial[blockIdx.x] = sh[t];
}

// Exclusive scan of block totals (nb <= 256).
__global__ void scan_partials_kernel(int* __restrict__ partial, int nb) {
    __shared__ int sh[256];
    int t = threadIdx.x;
    int v = (t < nb) ? partial[t] : 0;
    sh[t] = v;
    __syncthreads();
    for (int d = 1; d < 256; d <<= 1) {
        int add = (t >= d) ? sh[t - d] : 0;
        __syncthreads();
        sh[t] += add;
        __syncthreads();
    }
    if (t < nb) partial[t] = sh[t] - v;   // exclusive, in place
}

// Scatter edges into CSR order, pre-gathering src id and de_dot scalar.
__global__ void scatter_kernel(const int* __restrict__ edge_index,
                               const int* __restrict__ distances,
                               const int* __restrict__ prescan,
                               const int* __restrict__ partial,
                               const float* __restrict__ de_dot,
                               int* __restrict__ cursor,
                               int* __restrict__ csr_src,
                               float* __restrict__ csr_ded,
                               int n_edges) {
    int e = blockIdx.x * blockDim.x + threadIdx.x;
    if (e >= n_edges) return;
    int s = edge_index[e];
    int t = edge_index[n_edges + e];
    int base = prescan[t] + partial[t >> 8];
    int pos = atomicAdd(&cursor[t], 1);
    csr_src[base + pos] = s;
    csr_ded[base + pos] = de_dot[distances[e] / 50];
}

__device__ __forceinline__ float bf_lo(uint32 u) { return __uint_as_float(u << 16); }
__device__ __forceinline__ float bf_hi(uint32 u) { return __uint_as_float(u & 0xffff0000u); }

// One wave per node: fused attention + aggregation + normalize + relu.
// bf16 gathers (uint = 2 features per lane), edge loop unrolled x2 for ILP.
__global__ void aggregate_kernel(const u16* __restrict__ x16,
                                 const u16* __restrict__ y16,
                                 const u16* __restrict__ z16,
                                 const float* __restrict__ W2,
                                 const int* __restrict__ csr_src,
                                 const float* __restrict__ csr_ded,
                                 const int* __restrict__ prescan,
                                 const int* __restrict__ partial,
                                 const int* __restrict__ cnt,
                                 float* __restrict__ out,
                                 int n_nodes) {
    int lane = threadIdx.x & 63;
    int t = blockIdx.x * (blockDim.x >> 6) + (threadIdx.x >> 6);
    if (t >= n_nodes) return;

    int base = prescan[t] + partial[t >> 8];
    int deg = cnt[t];

    const uint32* __restrict__ yp = (const uint32*)y16;
    const uint32* __restrict__ xp = (const uint32*)x16;

    uint32 zv = ((const uint32*)z16)[(size_t)t * 64 + lane];
    float z0 = bf_lo(zv), z1 = bf_hi(zv);
    int f0 = lane * 2;
    float2 wv = *(const float2*)(W2 + f0);

    float acc0 = 0.f, acc1 = 0.f, attsum = 0.f;

    for (int b = 0; b < deg; b += 64) {
        int nb = min(64, deg - b);
        int sv = 0;
        float dedv = 0.f;
        if (lane < nb) {
            sv = csr_src[base + b + lane];
            dedv = csr_ded[base + b + lane];
        }
        int j = 0;
        for (; j + 2 <= nb; j += 2) {
            int sA = __shfl(sv, j, 64);
            int sB = __shfl(sv, j + 1, 64);
            float dA = __shfl(dedv, j, 64);
            float dB = __shfl(dedv, j + 1, 64);
            uint32 ya = yp[(size_t)sA * 64 + lane];
            uint32 yb = yp[(size_t)sB * 64 + lane];
            float hA0 = bf_lo(ya) + z0, hA1 = bf_hi(ya) + z1;
            float hB0 = bf_lo(yb) + z0, hB1 = bf_hi(yb) + z1;
            hA0 = fmaxf(hA0, 0.2f * hA0); hA1 = fmaxf(hA1, 0.2f * hA1);
            hB0 = fmaxf(hB0, 0.2f * hB0); hB1 = fmaxf(hB1, 0.2f * hB1);
            float pA = fmaf(hA0, wv.x, hA1 * wv.y);
            float pB = fmaf(hB0, wv.x, hB1 * wv.y);
#pragma unroll
            for (int off = 32; off > 0; off >>= 1) {
                pA += __shfl_xor(pA, off, 64);
                pB += __shfl_xor(pB, off, 64);
            }
            float sigA = 1.f / (1.f + __expf(-(pA + dA)));
            float sigB = 1.f / (1.f + __expf(-(pB + dB)));
            float attA = __expf(sigA);
            float attB = __expf(sigB);
            uint32 xa = xp[(size_t)sA * 64 + lane];
            uint32 xb = xp[(size_t)sB * 64 + lane];
            acc0 = fmaf(attA, bf_lo(xa), acc0);
            acc1 = fmaf(attA, bf_hi(xa), acc1);
            acc0 = fmaf(attB, bf_lo(xb), acc0);
            acc1 = fmaf(attB, bf_hi(xb), acc1);
            attsum += attA + attB;
        }
        for (; j < nb; ++j) {
            int sA = __shfl(sv, j, 64);
            float dA = __shfl(dedv, j, 64);
            uint32 ya = yp[(size_t)sA * 64 + lane];
            float hA0 = bf_lo(ya) + z0, hA1 = bf_hi(ya) + z1;
            hA0 = fmaxf(hA0, 0.2f * hA0); hA1 = fmaxf(hA1, 0.2f * hA1);
            float pA = fmaf(hA0, wv.x, hA1 * wv.y);
#pragma unroll
            for (int off = 32; off > 0; off >>= 1) pA += __shfl_xor(pA, off, 64);
            float attA = __expf(1.f / (1.f + __expf(-(pA + dA))));
            uint32 xa = xp[(size_t)sA * 64 + lane];
            acc0 = fmaf(attA, bf_lo(xa), acc0);
            acc1 = fmaf(attA, bf_hi(xa), acc1);
            attsum += attA;
        }
    }
    float inv = 1.f / (attsum + 1e-6f);
    float2 o;
    o.x = fmaxf(acc0 * inv, 0.f);
    o.y = fmaxf(acc1 * inv, 0.f);
    *(float2*)(out + (size_t)t * HIDDEN + f0) = o;
}

static inline size_t align16(size_t v) { return (v + 15) & ~(size_t)15; }

extern "C" void kernel_launch(void* const* d_in, const int* in_sizes, int n_in,
                              void* d_out, int out_size, void* d_ws, size_t ws_size,
                              hipStream_t stream) {
    const float* x          = (const float*)d_in[0];
    const int*   edge_index = (const int*)d_in[1];
    const int*   distances  = (const int*)d_in[2];
    const float* W1         = (const float*)d_in[3];
    const float* W2         = (const float*)d_in[4];
    const float* table      = (const float*)d_in[5];

    int n_nodes = in_sizes[0] / HIDDEN;
    int n_edges = in_sizes[1] / 2;
    float* out = (float*)d_out;

    // Workspace layout (16B-aligned sections)
    char* p = (char*)d_ws;
    int* cnt      = (int*)p;                 p += align16((size_t)n_nodes * 4);
    int* cursor   = (int*)p;                 p += align16((size_t)n_nodes * 4);
    int* prescan  = (int*)p;                 p += align16((size_t)n_nodes * 4);
    int* partial  = (int*)p;                 p += align16(256 * 4);
    int* csr_src  = (int*)p;                 p += align16((size_t)n_edges * 4);
    float* csr_ded = (float*)p;              p += align16((size_t)n_edges * 4);
    float* de_dot  = (float*)p;              p += align16(32 * 4);
    u16* W1T       = (u16*)p;                p += align16(256 * HIDDEN * 2);
    u16* y16       = (u16*)p;                p += align16((size_t)n_nodes * HIDDEN * 2);
    u16* z16       = (u16*)p;                p += align16((size_t)n_nodes * HIDDEN * 2);
    u16* x16       = (u16*)p;

    hipMemsetAsync(cnt, 0, (size_t)2 * align16((size_t)n_nodes * 4), stream);

    prep_kernel<<<128, 256, 0, stream>>>(W1, W1T);

    int ntiles = (n_nodes + 15) / 16;           // 3125
    int gblocks = (ntiles + 3) / 4;             // 4 waves (tiles) per 256-thr block
    mfma_gemm_kernel<<<gblocks, 256, 0, stream>>>(x, W1T, y16, z16, x16, n_nodes);

    const int* tgt = edge_index + n_edges;
    count_kernel<<<(n_edges + 255) / 256, 256, 0, stream>>>(tgt, cnt, n_edges,
                                                            table, W2, de_dot);

    int nb = (n_nodes + 255) / 256;
    scan_blocks_kernel<<<nb, 256, 0, stream>>>(cnt, prescan, partial, n_nodes);
    scan_partials_kernel<<<1, 256, 0, stream>>>(partial, nb);

    scatter_kernel<<<(n_edges + 255) / 256, 256, 0, stream>>>(
        edge_index, distances, prescan, partial, de_dot, cursor,
        csr_src, csr_ded, n_edges);

    const int waves_per_block = 4;
    int ablocks = (n_nodes + waves_per_block - 1) / waves_per_block;
    aggregate_kernel<<<ablocks, 64 * waves_per_block, 0, stream>>>(
        x16, y16, z16, W2, csr_src, csr_ded, prescan, partial, cnt, out, n_nodes);
}

// Round 6
// 219.918 us; speedup vs baseline: 1.6028x; 1.0407x over previous
//
#include <hip/hip_runtime.h>

#define HIDDEN 128
#define NBUCKETS 20

typedef unsigned int uint32;
typedef unsigned short u16;
typedef unsigned long long u64;
typedef __attribute__((ext_vector_type(8))) short bf16x8;
typedef __attribute__((ext_vector_type(4))) float f32x4;

__device__ __forceinline__ u16 f32_to_bf16(float f) {
    uint32 u = __float_as_uint(f);
    return (u16)((u + 0x7fffu + ((u >> 16) & 1u)) >> 16);
}

// W1T[n][k] (bf16, [256][128]): n<128 -> W1[k][n] (y cols), n>=128 -> W1[128+k][n-128] (z cols).
__global__ void prep_kernel(const float* __restrict__ W1, u16* __restrict__ W1T) {
    int idx = blockIdx.x * 256 + threadIdx.x;  // 0..32767
    int n = idx >> 7, k = idx & 127;
    int srow = (n < 128) ? k : (128 + k);
    int scol = n & 127;
    W1T[idx] = f32_to_bf16(W1[srow * HIDDEN + scol]);
}

// MFMA skinny GEMM, occupancy-optimized: one BLOCK (4 waves) per 16-row tile;
// each wave computes 4 col-tiles (16 MFMA). The 4 waves' A-loads share L1.
// Wave 0 also emits x16 (bf16 copy of x). 50000 % 16 == 0 -> guards nearly free.
__global__ __launch_bounds__(256)
void mfma_gemm_kernel(const float* __restrict__ x,
                      const u16* __restrict__ W1T,
                      u16* __restrict__ y16,
                      u16* __restrict__ z16,
                      u16* __restrict__ x16,
                      int n_nodes) {
    int row_base = blockIdx.x * 16;
    if (row_base >= n_nodes) return;
    int wave = threadIdx.x >> 6;
    int lane = threadIdx.x & 63;

    int m = lane & 15;        // A row / C col-within-tile
    int kb = lane >> 4;       // k-chunk 0..3 (8 elems each)
    int row = row_base + m;
    int rowc = (row < n_nodes) ? row : (n_nodes - 1);

    // A fragments for the 4 K-steps (f32 -> bf16 on the fly).
    bf16x8 afrag[4];
    const float* xr = x + (size_t)rowc * HIDDEN + kb * 8;
#pragma unroll
    for (int ks = 0; ks < 4; ++ks) {
        float4 v0 = *(const float4*)(xr + ks * 32);
        float4 v1 = *(const float4*)(xr + ks * 32 + 4);
        bf16x8 a;
        a[0] = (short)f32_to_bf16(v0.x); a[1] = (short)f32_to_bf16(v0.y);
        a[2] = (short)f32_to_bf16(v0.z); a[3] = (short)f32_to_bf16(v0.w);
        a[4] = (short)f32_to_bf16(v1.x); a[5] = (short)f32_to_bf16(v1.y);
        a[6] = (short)f32_to_bf16(v1.z); a[7] = (short)f32_to_bf16(v1.w);
        afrag[ks] = a;
        if (wave == 0 && row < n_nodes)
            *(bf16x8*)(x16 + (size_t)row * HIDDEN + ks * 32 + kb * 8) = a;
    }

#pragma unroll
    for (int ci = 0; ci < 4; ++ci) {
        int ct = wave * 4 + ci;     // this wave's col-tiles
        int col = ct * 16 + m;      // output col 0..255
        const u16* bp = W1T + (size_t)col * HIDDEN + kb * 8;
        f32x4 acc = {0.f, 0.f, 0.f, 0.f};
#pragma unroll
        for (int ks = 0; ks < 4; ++ks) {
            bf16x8 b = *(const bf16x8*)(bp + ks * 32);
            acc = __builtin_amdgcn_mfma_f32_16x16x32_bf16(afrag[ks], b, acc, 0, 0, 0);
        }
        // C/D: col = lane&15, row = (lane>>4)*4 + e   [HW-verified m89/m91]
        u16* dst = (col < HIDDEN) ? (y16 + col) : (z16 + col - HIDDEN);
        int r0 = row_base + kb * 4;
#pragma unroll
        for (int e = 0; e < 4; ++e)
            if (r0 + e < n_nodes)
                dst[(size_t)(r0 + e) * HIDDEN] = f32_to_bf16(acc[e]);
    }
}

// Histogram of target degrees; block 0 also computes de_dot[b] = table[b]·W2[128:].
__global__ void count_kernel(const int* __restrict__ tgt,
                             int* __restrict__ cnt, int n_edges,
                             const float* __restrict__ table,
                             const float* __restrict__ W2,
                             float* __restrict__ de_dot) {
    int e = blockIdx.x * blockDim.x + threadIdx.x;
    if (e < n_edges) atomicAdd(&cnt[tgt[e]], 1);
    if (blockIdx.x == 0 && threadIdx.x < NBUCKETS) {
        float a = 0.f;
        for (int k = 0; k < HIDDEN; ++k)
            a = fmaf(table[threadIdx.x * HIDDEN + k], W2[HIDDEN + k], a);
        de_dot[threadIdx.x] = a;
    }
}

// Per-block exclusive prescan of cnt + per-block totals.
__global__ void scan_blocks_kernel(const int* __restrict__ cnt,
                                   int* __restrict__ prescan,
                                   int* __restrict__ partial,
                                   int n_nodes) {
    __shared__ int sh[256];
    int t = threadIdx.x;
    int i = blockIdx.x * 256 + t;
    int v = (i < n_nodes) ? cnt[i] : 0;
    sh[t] = v;
    __syncthreads();
    for (int d = 1; d < 256; d <<= 1) {
        int add = (t >= d) ? sh[t - d] : 0;
        __syncthreads();
        sh[t] += add;
        __syncthreads();
    }
    if (i < n_nodes) prescan[i] = sh[t] - v;
    if (t == 255) partial[blockIdx.x] = sh[t];
}

// Exclusive scan of block totals (nb <= 256).
__global__ void scan_partials_kernel(int* __restrict__ partial, int nb) {
    __shared__ int sh[256];
    int t = threadIdx.x;
    int v = (t < nb) ? partial[t] : 0;
    sh[t] = v;
    __syncthreads();
    for (int d = 1; d < 256; d <<= 1) {
        int add = (t >= d) ? sh[t - d] : 0;
        __syncthreads();
        sh[t] += add;
        __syncthreads();
    }
    if (t < nb) partial[t] = sh[t] - v;   // exclusive, in place
}

// Scatter edges into CSR order; fused {src, de_dot} u64 record -> ONE random
// 8B write per edge (was two 4B writes to separate arrays).
__global__ void scatter_kernel(const int* __restrict__ edge_index,
                               const int* __restrict__ distances,
                               const int* __restrict__ prescan,
                               const int* __restrict__ partial,
                               const float* __restrict__ de_dot,
                               int* __restrict__ cursor,
                               u64* __restrict__ csr_sd,
                               int n_edges) {
    int e = blockIdx.x * blockDim.x + threadIdx.x;
    if (e >= n_edges) return;
    int s = edge_index[e];
    int t = edge_index[n_edges + e];
    float ded = de_dot[distances[e] / 50];
    int base = prescan[t] + partial[t >> 8];
    int pos = atomicAdd(&cursor[t], 1);
    csr_sd[base + pos] = ((u64)__float_as_uint(ded) << 32) | (uint32)s;
}

__device__ __forceinline__ float bf_lo(uint32 u) { return __uint_as_float(u << 16); }
__device__ __forceinline__ float bf_hi(uint32 u) { return __uint_as_float(u & 0xffff0000u); }

// One wave per node: fused attention + aggregation + normalize + relu.
// bf16 gathers (uint = 2 features per lane), edge loop unrolled x2 for ILP.
__global__ void aggregate_kernel(const u16* __restrict__ x16,
                                 const u16* __restrict__ y16,
                                 const u16* __restrict__ z16,
                                 const float* __restrict__ W2,
                                 const u64* __restrict__ csr_sd,
                                 const int* __restrict__ prescan,
                                 const int* __restrict__ partial,
                                 const int* __restrict__ cnt,
                                 float* __restrict__ out,
                                 int n_nodes) {
    int lane = threadIdx.x & 63;
    int t = blockIdx.x * (blockDim.x >> 6) + (threadIdx.x >> 6);
    if (t >= n_nodes) return;

    int base = prescan[t] + partial[t >> 8];
    int deg = cnt[t];

    const uint32* __restrict__ yp = (const uint32*)y16;
    const uint32* __restrict__ xp = (const uint32*)x16;

    uint32 zv = ((const uint32*)z16)[(size_t)t * 64 + lane];
    float z0 = bf_lo(zv), z1 = bf_hi(zv);
    int f0 = lane * 2;
    float2 wv = *(const float2*)(W2 + f0);

    float acc0 = 0.f, acc1 = 0.f, attsum = 0.f;

    for (int b = 0; b < deg; b += 64) {
        int nb = min(64, deg - b);
        int sv = 0;
        float dedv = 0.f;
        if (lane < nb) {
            uint2 rec = *(const uint2*)(csr_sd + base + b + lane);  // coalesced 8B
            sv = (int)rec.x;
            dedv = __uint_as_float(rec.y);
        }
        int j = 0;
        for (; j + 2 <= nb; j += 2) {
            int sA = __shfl(sv, j, 64);
            int sB = __shfl(sv, j + 1, 64);
            float dA = __shfl(dedv, j, 64);
            float dB = __shfl(dedv, j + 1, 64);
            uint32 ya = yp[(size_t)sA * 64 + lane];
            uint32 yb = yp[(size_t)sB * 64 + lane];
            float hA0 = bf_lo(ya) + z0, hA1 = bf_hi(ya) + z1;
            float hB0 = bf_lo(yb) + z0, hB1 = bf_hi(yb) + z1;
            hA0 = fmaxf(hA0, 0.2f * hA0); hA1 = fmaxf(hA1, 0.2f * hA1);
            hB0 = fmaxf(hB0, 0.2f * hB0); hB1 = fmaxf(hB1, 0.2f * hB1);
            float pA = fmaf(hA0, wv.x, hA1 * wv.y);
            float pB = fmaf(hB0, wv.x, hB1 * wv.y);
#pragma unroll
            for (int off = 32; off > 0; off >>= 1) {
                pA += __shfl_xor(pA, off, 64);
                pB += __shfl_xor(pB, off, 64);
            }
            float sigA = 1.f / (1.f + __expf(-(pA + dA)));
            float sigB = 1.f / (1.f + __expf(-(pB + dB)));
            float attA = __expf(sigA);
            float attB = __expf(sigB);
            uint32 xa = xp[(size_t)sA * 64 + lane];
            uint32 xb = xp[(size_t)sB * 64 + lane];
            acc0 = fmaf(attA, bf_lo(xa), acc0);
            acc1 = fmaf(attA, bf_hi(xa), acc1);
            acc0 = fmaf(attB, bf_lo(xb), acc0);
            acc1 = fmaf(attB, bf_hi(xb), acc1);
            attsum += attA + attB;
        }
        for (; j < nb; ++j) {
            int sA = __shfl(sv, j, 64);
            float dA = __shfl(dedv, j, 64);
            uint32 ya = yp[(size_t)sA * 64 + lane];
            float hA0 = bf_lo(ya) + z0, hA1 = bf_hi(ya) + z1;
            hA0 = fmaxf(hA0, 0.2f * hA0); hA1 = fmaxf(hA1, 0.2f * hA1);
            float pA = fmaf(hA0, wv.x, hA1 * wv.y);
#pragma unroll
            for (int off = 32; off > 0; off >>= 1) pA += __shfl_xor(pA, off, 64);
            float attA = __expf(1.f / (1.f + __expf(-(pA + dA))));
            uint32 xa = xp[(size_t)sA * 64 + lane];
            acc0 = fmaf(attA, bf_lo(xa), acc0);
            acc1 = fmaf(attA, bf_hi(xa), acc1);
            attsum += attA;
        }
    }
    float inv = 1.f / (attsum + 1e-6f);
    float2 o;
    o.x = fmaxf(acc0 * inv, 0.f);
    o.y = fmaxf(acc1 * inv, 0.f);
    *(float2*)(out + (size_t)t * HIDDEN + f0) = o;
}

static inline size_t align16(size_t v) { return (v + 15) & ~(size_t)15; }

extern "C" void kernel_launch(void* const* d_in, const int* in_sizes, int n_in,
                              void* d_out, int out_size, void* d_ws, size_t ws_size,
                              hipStream_t stream) {
    const float* x          = (const float*)d_in[0];
    const int*   edge_index = (const int*)d_in[1];
    const int*   distances  = (const int*)d_in[2];
    const float* W1         = (const float*)d_in[3];
    const float* W2         = (const float*)d_in[4];
    const float* table      = (const float*)d_in[5];

    int n_nodes = in_sizes[0] / HIDDEN;
    int n_edges = in_sizes[1] / 2;
    float* out = (float*)d_out;

    // Workspace layout (16B-aligned sections)
    char* p = (char*)d_ws;
    int* cnt      = (int*)p;                 p += align16((size_t)n_nodes * 4);
    int* cursor   = (int*)p;                 p += align16((size_t)n_nodes * 4);
    int* prescan  = (int*)p;                 p += align16((size_t)n_nodes * 4);
    int* partial  = (int*)p;                 p += align16(256 * 4);
    u64* csr_sd   = (u64*)p;                 p += align16((size_t)n_edges * 8);
    float* de_dot  = (float*)p;              p += align16(32 * 4);
    u16* W1T       = (u16*)p;                p += align16(256 * HIDDEN * 2);
    u16* y16       = (u16*)p;                p += align16((size_t)n_nodes * HIDDEN * 2);
    u16* z16       = (u16*)p;                p += align16((size_t)n_nodes * HIDDEN * 2);
    u16* x16       = (u16*)p;

    hipMemsetAsync(cnt, 0, (size_t)2 * align16((size_t)n_nodes * 4), stream);

    prep_kernel<<<128, 256, 0, stream>>>(W1, W1T);

    int ntiles = (n_nodes + 15) / 16;   // 3125; one block (4 waves) per tile
    mfma_gemm_kernel<<<ntiles, 256, 0, stream>>>(x, W1T, y16, z16, x16, n_nodes);

    const int* tgt = edge_index + n_edges;
    count_kernel<<<(n_edges + 255) / 256, 256, 0, stream>>>(tgt, cnt, n_edges,
                                                            table, W2, de_dot);

    int nb = (n_nodes + 255) / 256;
    scan_blocks_kernel<<<nb, 256, 0, stream>>>(cnt, prescan, partial, n_nodes);
    scan_partials_kernel<<<1, 256, 0, stream>>>(partial, nb);

    scatter_kernel<<<(n_edges + 255) / 256, 256, 0, stream>>>(
        edge_index, distances, prescan, partial, de_dot, cursor,
        csr_sd, n_edges);

    const int waves_per_block = 4;
    int ablocks = (n_nodes + waves_per_block - 1) / waves_per_block;
    aggregate_kernel<<<ablocks, 64 * waves_per_block, 0, stream>>>(
        x16, y16, z16, W2, csr_sd, prescan, partial, cnt, out, n_nodes);
}

// Round 7
// 180.597 us; speedup vs baseline: 1.9518x; 1.2177x over previous
//
#include <hip/hip_runtime.h>

#define HIDDEN 128
#define NBUCKETS 20

typedef unsigned int uint32;
typedef unsigned short u16;
typedef unsigned long long u64;
typedef __attribute__((ext_vector_type(8))) short bf16x8;
typedef __attribute__((ext_vector_type(4))) float f32x4;

__device__ __forceinline__ u16 f32_to_bf16(float f) {
    uint32 u = __float_as_uint(f);
    return (u16)((u + 0x7fffu + ((u >> 16) & 1u)) >> 16);
}

// k1: W1T transpose+convert (32768 elems = 128x256 exact), zero cnt, de_dot.
__global__ void prep_kernel(const float* __restrict__ W1, u16* __restrict__ W1T,
                            int* __restrict__ cnt, int n_nodes,
                            const float* __restrict__ table,
                            const float* __restrict__ W2,
                            float* __restrict__ de_dot) {
    int idx = blockIdx.x * 256 + threadIdx.x;
    int n = idx >> 7, k = idx & 127;
    int srow = (n < 128) ? k : (128 + k);
    W1T[idx] = f32_to_bf16(W1[srow * HIDDEN + (n & 127)]);
    for (int i = idx; i < n_nodes; i += 32768) cnt[i] = 0;
    if (blockIdx.x == 0 && threadIdx.x < NBUCKETS) {
        float a = 0.f;
        for (int kk = 0; kk < HIDDEN; ++kk)
            a = fmaf(table[threadIdx.x * HIDDEN + kk], W2[HIDDEN + kk], a);
        de_dot[threadIdx.x] = a;
    }
}

// k2: fused degree-histogram (1 edge/thread) + MFMA GEMM (one 16-row tile/block).
// A-tile cooperatively loaded+converted ONCE via LDS (fragment layout: slot c =
// ks*4+kb holds k-range [c*8, c*8+8)); C staged through per-wave LDS for
// coalesced bf16x8 stores. Also emits x16 from the staging pass.
__global__ __launch_bounds__(256)
void gemm_count_kernel(const float* __restrict__ x, const u16* __restrict__ W1T,
                       const int* __restrict__ tgt, int* __restrict__ cnt,
                       u16* __restrict__ y16, u16* __restrict__ z16,
                       u16* __restrict__ x16, int n_nodes, int n_edges) {
    __shared__ bf16x8 lds_a[16][16];   // [slot][row] : 4 KB
    __shared__ u16 lds_c[4][16][72];   // per-wave C staging (64 cols + pad) : 9 KB

    int tid = threadIdx.x;
    int e = blockIdx.x * 256 + tid;
    if (e < n_edges) atomicAdd(&cnt[tgt[e]], 1);

    int row_base = blockIdx.x * 16;
    if (row_base >= n_nodes) return;   // uniform per block

    // A staging + x16 emission: thread -> (row = tid>>4, k-chunk c = tid&15).
    {
        int row = tid >> 4, c = tid & 15;
        int node = row_base + row;
        bf16x8 a = {};
        if (node < n_nodes) {
            const float4* xp = (const float4*)(x + (size_t)node * HIDDEN + c * 8);
            float4 v0 = xp[0], v1 = xp[1];
            a[0] = (short)f32_to_bf16(v0.x); a[1] = (short)f32_to_bf16(v0.y);
            a[2] = (short)f32_to_bf16(v0.z); a[3] = (short)f32_to_bf16(v0.w);
            a[4] = (short)f32_to_bf16(v1.x); a[5] = (short)f32_to_bf16(v1.y);
            a[6] = (short)f32_to_bf16(v1.z); a[7] = (short)f32_to_bf16(v1.w);
            *(bf16x8*)(x16 + (size_t)node * HIDDEN + c * 8) = a;
        }
        lds_a[c][row] = a;
    }
    __syncthreads();

    int wave = tid >> 6, lane = tid & 63;
    int m = lane & 15, kb = lane >> 4;

    bf16x8 afrag[4];
#pragma unroll
    for (int ks = 0; ks < 4; ++ks) afrag[ks] = lds_a[ks * 4 + kb][m];

#pragma unroll
    for (int ci = 0; ci < 4; ++ci) {
        int col = wave * 64 + ci * 16 + m;   // wave owns 64 contiguous cols
        const u16* bp = W1T + (size_t)col * HIDDEN + kb * 8;
        f32x4 acc = {0.f, 0.f, 0.f, 0.f};
#pragma unroll
        for (int ks = 0; ks < 4; ++ks) {
            bf16x8 b = *(const bf16x8*)(bp + ks * 32);
            acc = __builtin_amdgcn_mfma_f32_16x16x32_bf16(afrag[ks], b, acc, 0, 0, 0);
        }
        // C/D: col = lane&15, row = (lane>>4)*4 + e2   [HW-verified m89/m91]
#pragma unroll
        for (int e2 = 0; e2 < 4; ++e2)
            lds_c[wave][kb * 4 + e2][ci * 16 + m] = f32_to_bf16(acc[e2]);
    }
    __syncthreads();

    // Coalesced readback: lane -> (row r = lane>>2, 16-col seg q = lane&3).
    {
        int r = lane >> 2, q = lane & 3;
        const u16* src = &lds_c[wave][r][q * 16];
        bf16x8 c0 = *(const bf16x8*)(src);
        bf16x8 c1 = *(const bf16x8*)(src + 8);
        int node = row_base + r;
        int colg = wave * 64 + q * 16;
        if (node < n_nodes) {
            u16* dst = (colg < HIDDEN) ? (y16 + (size_t)node * HIDDEN + colg)
                                       : (z16 + (size_t)node * HIDDEN + colg - HIDDEN);
            *(bf16x8*)dst = c0;
            *(bf16x8*)(dst + 8) = c1;
        }
    }
}

// k3: per-block exclusive prescan of cnt + block totals; re-zero cnt (cursor reuse).
__global__ void scan_blocks_kernel(int* __restrict__ cnt,
                                   int* __restrict__ prescan,
                                   int* __restrict__ partial,
                                   int n_nodes) {
    __shared__ int sh[256];
    int t = threadIdx.x;
    int i = blockIdx.x * 256 + t;
    int v = (i < n_nodes) ? cnt[i] : 0;
    sh[t] = v;
    __syncthreads();
    for (int d = 1; d < 256; d <<= 1) {
        int add = (t >= d) ? sh[t - d] : 0;
        __syncthreads();
        sh[t] += add;
        __syncthreads();
    }
    if (i < n_nodes) { prescan[i] = sh[t] - v; cnt[i] = 0; }
    if (t == 255) partial[blockIdx.x] = sh[t];
}

// k4: exclusive scan of block totals (nb <= 256).
__global__ void scan_partials_kernel(int* __restrict__ partial, int nb) {
    __shared__ int sh[256];
    int t = threadIdx.x;
    int v = (t < nb) ? partial[t] : 0;
    sh[t] = v;
    __syncthreads();
    for (int d = 1; d < 256; d <<= 1) {
        int add = (t >= d) ? sh[t - d] : 0;
        __syncthreads();
        sh[t] += add;
        __syncthreads();
    }
    if (t < nb) partial[t] = sh[t] - v;
}

// k5: scatter edges into CSR order; cnt doubles as cursor (ends back at deg).
__global__ void scatter_kernel(const int* __restrict__ edge_index,
                               const int* __restrict__ distances,
                               const int* __restrict__ prescan,
                               const int* __restrict__ partial,
                               const float* __restrict__ de_dot,
                               int* __restrict__ cnt,
                               u64* __restrict__ csr_sd,
                               int n_edges) {
    int e = blockIdx.x * blockDim.x + threadIdx.x;
    if (e >= n_edges) return;
    int s = edge_index[e];
    int t = edge_index[n_edges + e];
    float ded = de_dot[distances[e] / 50];
    int base = prescan[t] + partial[t >> 8];
    int pos = atomicAdd(&cnt[t], 1);
    csr_sd[base + pos] = ((u64)__float_as_uint(ded) << 32) | (uint32)s;
}

__device__ __forceinline__ float bf_lo(uint32 u) { return __uint_as_float(u << 16); }
__device__ __forceinline__ float bf_hi(uint32 u) { return __uint_as_float(u & 0xffff0000u); }

// k6: one wave per node: fused attention + aggregation + normalize + relu.
__global__ void aggregate_kernel(const u16* __restrict__ x16,
                                 const u16* __restrict__ y16,
                                 const u16* __restrict__ z16,
                                 const float* __restrict__ W2,
                                 const u64* __restrict__ csr_sd,
                                 const int* __restrict__ prescan,
                                 const int* __restrict__ partial,
                                 const int* __restrict__ cnt,
                                 float* __restrict__ out,
                                 int n_nodes) {
    int lane = threadIdx.x & 63;
    int t = blockIdx.x * (blockDim.x >> 6) + (threadIdx.x >> 6);
    if (t >= n_nodes) return;

    int base = prescan[t] + partial[t >> 8];
    int deg = cnt[t];

    const uint32* __restrict__ yp = (const uint32*)y16;
    const uint32* __restrict__ xp = (const uint32*)x16;

    uint32 zv = ((const uint32*)z16)[(size_t)t * 64 + lane];
    float z0 = bf_lo(zv), z1 = bf_hi(zv);
    int f0 = lane * 2;
    float2 wv = *(const float2*)(W2 + f0);

    float acc0 = 0.f, acc1 = 0.f, attsum = 0.f;

    for (int b = 0; b < deg; b += 64) {
        int nb = min(64, deg - b);
        int sv = 0;
        float dedv = 0.f;
        if (lane < nb) {
            uint2 rec = *(const uint2*)(csr_sd + base + b + lane);
            sv = (int)rec.x;
            dedv = __uint_as_float(rec.y);
        }
        int j = 0;
        for (; j + 2 <= nb; j += 2) {
            int sA = __shfl(sv, j, 64);
            int sB = __shfl(sv, j + 1, 64);
            float dA = __shfl(dedv, j, 64);
            float dB = __shfl(dedv, j + 1, 64);
            uint32 ya = yp[(size_t)sA * 64 + lane];
            uint32 yb = yp[(size_t)sB * 64 + lane];
            float hA0 = bf_lo(ya) + z0, hA1 = bf_hi(ya) + z1;
            float hB0 = bf_lo(yb) + z0, hB1 = bf_hi(yb) + z1;
            hA0 = fmaxf(hA0, 0.2f * hA0); hA1 = fmaxf(hA1, 0.2f * hA1);
            hB0 = fmaxf(hB0, 0.2f * hB0); hB1 = fmaxf(hB1, 0.2f * hB1);
            float pA = fmaf(hA0, wv.x, hA1 * wv.y);
            float pB = fmaf(hB0, wv.x, hB1 * wv.y);
#pragma unroll
            for (int off = 32; off > 0; off >>= 1) {
                pA += __shfl_xor(pA, off, 64);
                pB += __shfl_xor(pB, off, 64);
            }
            float sigA = 1.f / (1.f + __expf(-(pA + dA)));
            float sigB = 1.f / (1.f + __expf(-(pB + dB)));
            float attA = __expf(sigA);
            float attB = __expf(sigB);
            uint32 xa = xp[(size_t)sA * 64 + lane];
            uint32 xb = xp[(size_t)sB * 64 + lane];
            acc0 = fmaf(attA, bf_lo(xa), acc0);
            acc1 = fmaf(attA, bf_hi(xa), acc1);
            acc0 = fmaf(attB, bf_lo(xb), acc0);
            acc1 = fmaf(attB, bf_hi(xb), acc1);
            attsum += attA + attB;
        }
        for (; j < nb; ++j) {
            int sA = __shfl(sv, j, 64);
            float dA = __shfl(dedv, j, 64);
            uint32 ya = yp[(size_t)sA * 64 + lane];
            float hA0 = bf_lo(ya) + z0, hA1 = bf_hi(ya) + z1;
            hA0 = fmaxf(hA0, 0.2f * hA0); hA1 = fmaxf(hA1, 0.2f * hA1);
            float pA = fmaf(hA0, wv.x, hA1 * wv.y);
#pragma unroll
            for (int off = 32; off > 0; off >>= 1) pA += __shfl_xor(pA, off, 64);
            float attA = __expf(1.f / (1.f + __expf(-(pA + dA))));
            uint32 xa = xp[(size_t)sA * 64 + lane];
            acc0 = fmaf(attA, bf_lo(xa), acc0);
            acc1 = fmaf(attA, bf_hi(xa), acc1);
            attsum += attA;
        }
    }
    float inv = 1.f / (attsum + 1e-6f);
    float2 o;
    o.x = fmaxf(acc0 * inv, 0.f);
    o.y = fmaxf(acc1 * inv, 0.f);
    *(float2*)(out + (size_t)t * HIDDEN + f0) = o;
}

static inline size_t align16(size_t v) { return (v + 15) & ~(size_t)15; }

extern "C" void kernel_launch(void* const* d_in, const int* in_sizes, int n_in,
                              void* d_out, int out_size, void* d_ws, size_t ws_size,
                              hipStream_t stream) {
    const float* x          = (const float*)d_in[0];
    const int*   edge_index = (const int*)d_in[1];
    const int*   distances  = (const int*)d_in[2];
    const float* W1         = (const float*)d_in[3];
    const float* W2         = (const float*)d_in[4];
    const float* table      = (const float*)d_in[5];

    int n_nodes = in_sizes[0] / HIDDEN;
    int n_edges = in_sizes[1] / 2;
    float* out = (float*)d_out;

    // Workspace layout (16B-aligned sections)
    char* p = (char*)d_ws;
    int* cnt      = (int*)p;                 p += align16((size_t)n_nodes * 4);
    int* prescan  = (int*)p;                 p += align16((size_t)n_nodes * 4);
    int* partial  = (int*)p;                 p += align16(256 * 4);
    u64* csr_sd   = (u64*)p;                 p += align16((size_t)n_edges * 8);
    float* de_dot  = (float*)p;              p += align16(32 * 4);
    u16* W1T       = (u16*)p;                p += align16(256 * HIDDEN * 2);
    u16* y16       = (u16*)p;                p += align16((size_t)n_nodes * HIDDEN * 2);
    u16* z16       = (u16*)p;                p += align16((size_t)n_nodes * HIDDEN * 2);
    u16* x16       = (u16*)p;

    const int* tgt = edge_index + n_edges;

    prep_kernel<<<128, 256, 0, stream>>>(W1, W1T, cnt, n_nodes, table, W2, de_dot);

    int ntiles = (n_nodes + 15) / 16;                 // 3125
    int eblocks = (n_edges + 255) / 256;              // 3125
    int gblocks = (ntiles > eblocks) ? ntiles : eblocks;
    gemm_count_kernel<<<gblocks, 256, 0, stream>>>(x, W1T, tgt, cnt,
                                                   y16, z16, x16, n_nodes, n_edges);

    int nb = (n_nodes + 255) / 256;
    scan_blocks_kernel<<<nb, 256, 0, stream>>>(cnt, prescan, partial, n_nodes);
    scan_partials_kernel<<<1, 256, 0, stream>>>(partial, nb);

    scatter_kernel<<<eblocks, 256, 0, stream>>>(
        edge_index, distances, prescan, partial, de_dot, cnt, csr_sd, n_edges);

    const int waves_per_block = 4;
    int ablocks = (n_nodes + waves_per_block - 1) / waves_per_block;
    aggregate_kernel<<<ablocks, 64 * waves_per_block, 0, stream>>>(
        x16, y16, z16, W2, csr_sd, prescan, partial, cnt, out, n_nodes);
}